// Round 9
// baseline (287.166 us; speedup 1.0000x reference)
//
#include <hip/hip_runtime.h>
#include <hip/hip_bf16.h>
#include <stdint.h>

// B=4, S=2048, D=1024, H=16, HD=64. Inputs fp32, OUTPUT fp32.
// Intermediates bf16. Workspace 64 MiB (exact fit):
//   aws  [0, 16MiB)    bf16 [B*S][D]   (wT1 overlays; dead before attn)
//   qkv  [16, 64MiB)   bf16 q|k|v each; V stored TRANSPOSED [B,H,HD,S] (R10)
//   wT2 overlays qws, written AFTER attn consumed Q.
// R13: hidden pre-converted to bf16 into d_out (dead until proj GEMM).
// R16: gemm_bt + T1 XCD-chunked block swizzle.
// R17: attn KVBLK=128 (half the barriers/stage boundaries; same bytes,
//      same MFMA/key); prep kernels fused (cvt + attn_w transpose).
#define B_ 4
#define S_ 2048
#define D_ 1024
#define H_ 16
#define HD_ 64

typedef __bf16 bf16_t;
typedef bf16_t bf16x8 __attribute__((ext_vector_type(8)));
typedef bf16_t bf16x4 __attribute__((ext_vector_type(4)));
typedef float f32x4 __attribute__((ext_vector_type(4)));
typedef float f32x16 __attribute__((ext_vector_type(16)));

__device__ __forceinline__ bf16x8 cvt8(f32x4 lo, f32x4 hi) {
  bf16x8 r;
#pragma unroll
  for (int i = 0; i < 4; i++) {
    r[i] = (bf16_t)lo[i];
    r[i + 4] = (bf16_t)hi[i];
  }
  return r;
}

// Async global->LDS, 16B/lane; LDS dest = wave-uniform base + lane*16.
__device__ __forceinline__ void async_lds16(const bf16_t* g, bf16_t* l) {
  __builtin_amdgcn_global_load_lds(
      (const __attribute__((address_space(1))) void*)g,
      (__attribute__((address_space(3))) void*)l, 16, 0, 0);
}

// pack two f32 -> one u32 of two bf16 (elem0 = low 16 bits); compiler fuses.
__device__ __forceinline__ uint32_t pk2(float a, float b) {
  union {
    bf16_t h[2];
    uint32_t u;
  } x;
  x.h[0] = (bf16_t)a;
  x.h[1] = (bf16_t)b;
  return x.u;
}

// v_permlane32_swap_b32: a.hi_lanes <-> b.lo_lanes.
__device__ __forceinline__ void swap32(uint32_t& a, uint32_t& b) {
  asm("v_permlane32_swap_b32 %0, %1" : "+v"(a), "+v"(b));
}

union PAU {
  uint32_t w[4];
  bf16x8 v;
};

// ---------------------------------------------------------------------------
// Fused prep (R17): blocks [0,4096): hidden fp32->bf16 (8 elems/thread);
// blocks [4096,7168): attn_w [1024][3072] -> wT1 bf16 [3072][1024].
// Each block takes exactly one branch (barrier use is block-uniform).
// ---------------------------------------------------------------------------
__global__ __launch_bounds__(256) void prep(
    const float* __restrict__ hidden, bf16_t* __restrict__ hb,
    const float* __restrict__ attn_w, bf16_t* __restrict__ wT1) {
  __shared__ bf16_t tile[32][33];
  const int bid = blockIdx.x;
  if (bid < 4096) {
    size_t i = ((size_t)bid * 256 + threadIdx.x) * 8;
    f32x4 lo = *(const f32x4*)(hidden + i);
    f32x4 hi = *(const f32x4*)(hidden + i + 4);
    *(bf16x8*)(hb + i) = cvt8(lo, hi);
  } else {
    const int b2 = bid - 4096;  // 0..3071
    const int c0 = (b2 % 96) * 32, r0 = (b2 / 96) * 32;
    const int tx = threadIdx.x & 31, ty = threadIdx.x >> 5;
    const int R = 1024, C = 3072;
    for (int i = ty; i < 32; i += 8)
      tile[i][tx] = (bf16_t)attn_w[(size_t)(r0 + i) * C + c0 + tx];
    __syncthreads();
    for (int i = ty; i < 32; i += 8)
      wT1[(size_t)(c0 + i) * R + r0 + tx] = tile[tx][i];
  }
}

// ---------------------------------------------------------------------------
// Weight cvt+transpose: in fp32 [R][C] -> out bf16 [C][R]. (proj_w, post-attn)
// ---------------------------------------------------------------------------
__global__ void transpose_cvt(const float* __restrict__ in,
                              bf16_t* __restrict__ out, int R, int C) {
  __shared__ bf16_t tile[32][33];
  int c0 = blockIdx.x * 32, r0 = blockIdx.y * 32;
  int tx = threadIdx.x, ty = threadIdx.y;  // 32 x 8
  for (int i = ty; i < 32; i += 8)
    tile[i][tx] = (bf16_t)in[(size_t)(r0 + i) * C + c0 + tx];
  __syncthreads();
  for (int i = ty; i < 32; i += 8)
    out[(size_t)(c0 + i) * R + r0 + tx] = tile[tx][i];
}

// ---------------------------------------------------------------------------
// GEMM (m97 structure, R16 = 128x128 2-barrier + XCD-chunked swizzle):
// C[m,n] = sum_k A[m,k]*BT[n,k] + bias[n].
// mode 0: fp32 store. mode 1: QKV scatter (bf16); V written TRANSPOSED
// [bb][H][HD][S] so attention can stage V^T via global_load_lds.
// ---------------------------------------------------------------------------
__global__ __launch_bounds__(256) void gemm_bt(
    const void* __restrict__ A, const bf16_t* __restrict__ BT,
    const float* __restrict__ bias, float* __restrict__ Cout,
    bf16_t* __restrict__ qws, bf16_t* __restrict__ kws,
    bf16_t* __restrict__ vws, int M, int Nw, int K, int mode, int a_is_f32,
    size_t a_off) {
  __shared__ bf16_t As[128 * 32];  // [m][k]
  __shared__ bf16_t Bs[128 * 32];  // [n][k]
  const int tid = threadIdx.x;
  const int wave = tid >> 6, lane = tid & 63;
  const int quad = lane >> 4, tn = lane & 15;
  const int lid = blockIdx.y * gridDim.x + blockIdx.x;
  const int cpx = (gridDim.x * gridDim.y) >> 3;
  const int nl = (lid & 7) * cpx + (lid >> 3);
  const int m_blk = (nl / gridDim.x) * 128, n_blk = (nl % gridDim.x) * 128;
  const int wm = (wave >> 1) * 64, wn = (wave & 1) * 64;

  f32x4 acc[4][4] = {};

  const int srow = wave * 32 + (lane >> 2);
  const int scol = (lane & 3) * 8;
  size_t aoff = a_off + (size_t)(m_blk + srow) * K + scol;
  const bf16_t* gb = BT + (size_t)(n_blk + srow) * K + scol;
  bf16_t* lbB0 = &Bs[wave * 1024];
  bf16_t* lbB1 = &Bs[wave * 1024 + 512];
  bf16_t* laA0 = &As[wave * 1024];
  bf16_t* laA1 = &As[wave * 1024 + 512];

  for (int k0 = 0; k0 < K; k0 += 32) {
    async_lds16(gb, lbB0);
    async_lds16(gb + (size_t)16 * K, lbB1);
    if (a_is_f32) {
      const float* gaf = (const float*)A + aoff;
      f32x4 a00 = *(const f32x4*)gaf;
      f32x4 a01 = *(const f32x4*)(gaf + 4);
      f32x4 a10 = *(const f32x4*)(gaf + (size_t)16 * K);
      f32x4 a11 = *(const f32x4*)(gaf + (size_t)16 * K + 4);
      *(bf16x8*)&As[srow * 32 + scol] = cvt8(a00, a01);
      *(bf16x8*)&As[(srow + 16) * 32 + scol] = cvt8(a10, a11);
    } else {
      const bf16_t* ga = (const bf16_t*)A + aoff;
      async_lds16(ga, laA0);
      async_lds16(ga + (size_t)16 * K, laA1);
    }
    aoff += 32;
    gb += 32;
    __syncthreads();

    bf16x8 af[4], bfr[4];
#pragma unroll
    for (int i = 0; i < 4; i++)
      af[i] = *(const bf16x8*)&As[(wm + i * 16 + tn) * 32 + quad * 8];
#pragma unroll
    for (int i = 0; i < 4; i++)
      bfr[i] = *(const bf16x8*)&Bs[(wn + i * 16 + tn) * 32 + quad * 8];
#pragma unroll
    for (int mi = 0; mi < 4; mi++)
#pragma unroll
      for (int ni = 0; ni < 4; ni++)
        acc[mi][ni] = __builtin_amdgcn_mfma_f32_16x16x32_bf16(af[mi], bfr[ni],
                                                              acc[mi][ni], 0, 0, 0);
    __syncthreads();
  }

  // Epilogue. C/D: col(n)=lane&15, row(m)=quad*4+r  [m89-verified]
  if (mode == 0) {  // fp32 final store
#pragma unroll
    for (int ni = 0; ni < 4; ni++) {
      int n = n_blk + wn + ni * 16 + tn;
      float bv = bias[n];
#pragma unroll
      for (int mi = 0; mi < 4; mi++)
#pragma unroll
        for (int r = 0; r < 4; r++) {
          int m = m_blk + wm + mi * 16 + quad * 4 + r;
          Cout[(size_t)m * Nw + n] = acc[mi][ni][r] + bv;
        }
    }
  } else {  // QKV scatter. sec is block-uniform (n_blk multiple of 128).
#pragma unroll
    for (int ni = 0; ni < 4; ni++) {
      int n = n_blk + wn + ni * 16 + tn;
      int sec = n >> 10;
      int hn = n & 1023;
      int hh = hn >> 6, hd = hn & 63;
      float bv = bias[n];
      if (sec == 2) {  // V^T [bb][H][HD][S]: 4 consecutive s -> 8B store
#pragma unroll
        for (int mi = 0; mi < 4; mi++) {
          int m = m_blk + wm + mi * 16 + quad * 4;
          int bb = m >> 11, s = m & 2047;
          bf16x4 pk;
#pragma unroll
          for (int r = 0; r < 4; r++) pk[r] = (bf16_t)(acc[mi][ni][r] + bv);
          *(bf16x4*)&vws[((size_t)(bb * H_ + hh) * HD_ + hd) * S_ + s] = pk;
        }
      } else {
        bf16_t* dst = (sec == 0) ? qws : kws;
#pragma unroll
        for (int mi = 0; mi < 4; mi++)
#pragma unroll
          for (int r = 0; r < 4; r++) {
            int m = m_blk + wm + mi * 16 + quad * 4 + r;
            int bb = m >> 11, s = m & 2047;
            dst[((size_t)(bb * H_ + hh) * S_ + s) * HD_ + hd] =
                (bf16_t)(acc[mi][ni][r] + bv);
          }
      }
    }
  }
}

// ---------------------------------------------------------------------------
// Causal flash attention, R17: persistent-pair blocks, KVBLK=128.
//  - R17: 128-key tiles halve the per-tile barrier/stage boundaries
//    (36 -> 18 per block pair); bytes staged, MFMA/key, VALU/key unchanged.
//    LDS 64KB (1 persistent block/CU); st[4] f32x16 QK accumulators.
//  - (R14) grid 256 = 1 block/CU; two complementary q-tiles per block
//    (task qt = 7-pj then pj): exactly 18 tile-units each, perfect balance.
//  - (R12) striped queries across 8 waves; row-sum via MFMA (P x ones).
//  - (R11) XCD mapping: 8 heads/XCD. setprio on MFMA clusters.
//  - (R10) swapped QK^T (32x32x16), in-register P via pk2+permlane32_swap,
//    K/V^T staged via global_load_lds w16 + slot-swizzle, double-buffered,
//    1 barrier/tile, T13 defer-max (THR=8, log2 domain).
// ---------------------------------------------------------------------------
__global__ __launch_bounds__(512, 2) void attn_kernel(
    const bf16_t* __restrict__ Qw, const bf16_t* __restrict__ Kw,
    const bf16_t* __restrict__ VTw, bf16_t* __restrict__ Ow) {
  __shared__ bf16_t Ks[2][128 * 64];  // [key][hd], slot-swizzled (32KB)
  __shared__ bf16_t Vt[2][64 * 128];  // [hd][key], slot-swizzled (32KB)

  const int tid = threadIdx.x;
  const int wave = tid >> 6, lane = tid & 63;  // wave 0..7
  const int lq = lane & 31;   // query slot (and d-col) index within wave
  const int h = lane >> 5;    // half: k-subrange selector in A/B frags
  const int qoff = h * 4;     // C-layout row offset
  const int bid = blockIdx.x;          // 0..255
  const int j = bid >> 3;              // 0..31 within this XCD
  const int bh = (bid & 7) * 8 + (j >> 2);
  const int pj = j & 3;                // pair index 0..3

  const bf16_t* Qb = Qw + (size_t)bh * S_ * HD_;
  const bf16_t* Kb = Kw + (size_t)bh * S_ * HD_;
  const bf16_t* VTb = VTw + (size_t)bh * HD_ * S_;

  const float kScale = 0.125f * 1.44269504088896f;  // 1/sqrt(64) * log2(e)

  // ones B-frag for the row-sum MFMA
  bf16x8 onesf;
#pragma unroll
  for (int jj = 0; jj < 8; jj++) onesf[jj] = (bf16_t)1.0f;

  const float NEG = -30000.0f;
  const int b = bh >> 4, hh = bh & 15;

  // staging (per wave 4 async calls x 1KB):
  // K tile [128][64]: wave rows [wave*16, +16), 2 calls x 8 rows, 8 slots.
  const int krow = wave * 16 + (lane >> 3);
  const int ksl = lane & 7;
  const bf16_t* kpA = Kb + (size_t)krow * HD_ + ((ksl ^ (krow & 7)) * 8);
  const bf16_t* kpB =
      Kb + (size_t)(krow + 8) * HD_ + ((ksl ^ ((krow + 8) & 7)) * 8);
  // V^T tile [64][128]: wave rows [wave*8, +8), 2 calls x 4 rows, 16 slots.
  const int vrow = wave * 8 + (lane >> 4);
  const int vsl = lane & 15;
  const bf16_t* vpA = VTb + (size_t)vrow * S_ + ((vsl ^ (vrow & 7)) * 8);
  const bf16_t* vpB =
      VTb + (size_t)(vrow + 4) * S_ + ((vsl ^ ((vrow + 4) & 7)) * 8);

#define STAGE(buf, kt)                                                     \
  do {                                                                     \
    async_lds16(kpA + (size_t)(kt) * (128 * HD_), &Ks[buf][wave * 1024]);  \
    async_lds16(kpB + (size_t)(kt) * (128 * HD_),                          \
                &Ks[buf][wave * 1024 + 512]);                              \
    async_lds16(vpA + (size_t)(kt) * 128, &Vt[buf][wave * 1024]);          \
    async_lds16(vpB + (size_t)(kt) * 128, &Vt[buf][wave * 1024 + 512]);    \
  } while (0)

  for (int task = 0; task < 2; task++) {
    const int qt = task == 0 ? (7 - pj) : pj;  // long first, then short
    const int qb = qt * 256;
    const int qa = qb + ((lq >> 3) << 6) + wave * 8 + (lq & 7);

    // Q B-frags: B[k][n=lq], k = h*8+j within each 16-wide slice kg.
    bf16x8 qf[4];
#pragma unroll
    for (int kg = 0; kg < 4; kg++) {
      bf16x8 v = *(const bf16x8*)&Qb[(size_t)qa * HD_ + kg * 16 + h * 8];
#pragma unroll
      for (int jj = 0; jj < 8; jj++) v[jj] = (bf16_t)((float)v[jj] * kScale);
      qf[kg] = v;
    }

    f32x16 o0 = {}, o1 = {};  // O[q-slot][d]: d = dblk*32+lq
    f32x16 ls = {};           // row-sum accumulator (same C-layout as o)
    float mrow = NEG;

    const int kt_max = (qb + 255) >> 7;  // inclusive; 2qt+1

    if (task) __syncthreads();  // all waves done reading prev task's bufs
    STAGE(0, 0);

    for (int kt = 0; kt <= kt_max; kt++) {
      __syncthreads();  // drains vmcnt: buf[kt&1] staged; prev readers done
      if (kt < kt_max) STAGE((kt + 1) & 1, kt + 1);

      const bf16_t* KsB = Ks[kt & 1];
      const bf16_t* VtB = Vt[kt & 1];
      const int rsl = lq & 7;  // row-swizzle (same for lq, 32+lq, b*32+lq)

      // QK^T swapped: st[bk] = keys [bk*32, +32) of this 128-key tile.
      f32x16 st[4] = {{}, {}, {}, {}};
      __builtin_amdgcn_s_setprio(1);
#pragma unroll
      for (int kg = 0; kg < 4; kg++) {
        const int slot = kg * 2 + h;
#pragma unroll
        for (int bk = 0; bk < 4; bk++) {
          bf16x8 kf = *(const bf16x8*)&KsB[(bk * 32 + lq) * 64 +
                                           ((slot ^ rsl) * 8)];
          st[bk] =
              __builtin_amdgcn_mfma_f32_32x32x16_bf16(kf, qf[kg], st[bk], 0, 0, 0);
        }
      }
      __builtin_amdgcn_s_setprio(0);
      // causal mask only on the last two tiles of a task. key(reg r) =
      // kt*128 + bk*32 + (r&3) + 8*(r>>2) + 4h  [m74/m101 C-layout]
      if (kt * 128 + 127 > qb) {
#pragma unroll
        for (int bk = 0; bk < 4; bk++)
#pragma unroll
          for (int r = 0; r < 16; r++) {
            int key = kt * 128 + bk * 32 + (r & 3) + 8 * (r >> 2) + qoff;
            if (key > qa) st[bk][r] = NEG;
          }
      }
      // row max: in-lane tree (63 fmax) + one cross-half exchange
      float mx;
      {
        float m4[4];
#pragma unroll
        for (int bk = 0; bk < 4; bk++) {
          float a0 = fmaxf(fmaxf(st[bk][0], st[bk][1]),
                           fmaxf(st[bk][2], st[bk][3]));
          float a1 = fmaxf(fmaxf(st[bk][4], st[bk][5]),
                           fmaxf(st[bk][6], st[bk][7]));
          float a2 = fmaxf(fmaxf(st[bk][8], st[bk][9]),
                           fmaxf(st[bk][10], st[bk][11]));
          float a3 = fmaxf(fmaxf(st[bk][12], st[bk][13]),
                           fmaxf(st[bk][14], st[bk][15]));
          m4[bk] = fmaxf(fmaxf(a0, a1), fmaxf(a2, a3));
        }
        mx = fmaxf(fmaxf(m4[0], m4[1]), fmaxf(m4[2], m4[3]));
        mx = fmaxf(mx, __shfl_xor(mx, 32, 64));
      }

      // T13 defer-max: rescale only when max grew by > 8 (log2 domain)
      if (__any(mx > mrow + 8.f)) {
        float mnew = fmaxf(mrow, mx);
        float alpha = exp2f(mrow - mnew);
        mrow = mnew;
#pragma unroll
        for (int r = 0; r < 16; r++) {
          float ar = __shfl(alpha, (r & 3) + 8 * (r >> 2) + qoff, 64);
          o0[r] *= ar;
          o1[r] *= ar;
          ls[r] *= ar;
        }
      }
      // P = exp2(st - m) (bounded by 2^8 when deferred)
#pragma unroll
      for (int bk = 0; bk < 4; bk++)
#pragma unroll
        for (int r = 0; r < 16; r++) st[bk][r] = exp2f(st[bk][r] - mrow);

      // P -> PV A-frags, in-register: per 32-key block, pack + permlane.
      // pa[kg] covers keys kg*16 + 8h + j (verified pattern, R10).
      PAU pa[8];
#pragma unroll
      for (int bk = 0; bk < 4; bk++) {
        uint32_t w[8];
#pragma unroll
        for (int i = 0; i < 8; i++)
          w[i] = pk2(st[bk][2 * i], st[bk][2 * i + 1]);
        swap32(w[0], w[2]);
        swap32(w[1], w[3]);
        swap32(w[4], w[6]);
        swap32(w[5], w[7]);
        pa[2 * bk].w[0] = w[0];
        pa[2 * bk].w[1] = w[1];
        pa[2 * bk].w[2] = w[2];
        pa[2 * bk].w[3] = w[3];
        pa[2 * bk + 1].w[0] = w[4];
        pa[2 * bk + 1].w[1] = w[5];
        pa[2 * bk + 1].w[2] = w[6];
        pa[2 * bk + 1].w[3] = w[7];
      }

      // PV: O[q][d] += P*V; B-frag = Vt[d = dblk*32+lq][key kg*16+8h+j].
      // Row-sum: ls += P * ones (MFMA; C-layout == o's).
      __builtin_amdgcn_s_setprio(1);
#pragma unroll
      for (int kg = 0; kg < 8; kg++) {
        const int slot = kg * 2 + h;  // 0..15
        bf16x8 vf0 = *(const bf16x8*)&VtB[lq * 128 + ((slot ^ rsl) * 8)];
        bf16x8 vf1 =
            *(const bf16x8*)&VtB[(32 + lq) * 128 + ((slot ^ rsl) * 8)];
        o0 = __builtin_amdgcn_mfma_f32_32x32x16_bf16(pa[kg].v, vf0, o0, 0, 0, 0);
        o1 = __builtin_amdgcn_mfma_f32_32x32x16_bf16(pa[kg].v, vf1, o1, 0, 0, 0);
        ls = __builtin_amdgcn_mfma_f32_32x32x16_bf16(pa[kg].v, onesf, ls, 0, 0, 0);
      }
      __builtin_amdgcn_s_setprio(0);
    }

    // normalize + store merged heads [b][s][hh*64+d] (bf16). ls reg-local.
#pragma unroll
    for (int r = 0; r < 16; r++) {
      int qr = (r & 3) + 8 * (r >> 2) + qoff;  // q-slot of this C row
      int q = qb + ((qr >> 3) << 6) + wave * 8 + (qr & 7);  // striped remap
      float inv = 1.f / fmaxf(ls[r], 1e-30f);
      bf16_t* dst = Ow + (size_t)(b * S_ + q) * D_ + hh * HD_;
      dst[lq] = (bf16_t)(o0[r] * inv);
      dst[32 + lq] = (bf16_t)(o1[r] * inv);
    }
  }
#undef STAGE
}

// ---------------------------------------------------------------------------
extern "C" void kernel_launch(void* const* d_in, const int* in_sizes, int n_in,
                              void* d_out, int out_size, void* d_ws,
                              size_t ws_size, hipStream_t stream) {
  const float* hidden = nullptr;
  const float* attn_w = nullptr;
  const float* attn_b = nullptr;
  const float* proj_w = nullptr;
  const float* proj_b = nullptr;
  for (int i = 0; i < n_in; ++i) {
    switch (in_sizes[i]) {
      case 8388608: hidden = (const float*)d_in[i]; break;
      case 3145728: attn_w = (const float*)d_in[i]; break;
      case 3072:    attn_b = (const float*)d_in[i]; break;
      case 1048576: proj_w = (const float*)d_in[i]; break;
      case 1024:    proj_b = (const float*)d_in[i]; break;
      default: break;
    }
  }
  if (!hidden) hidden = (const float*)d_in[0];
  if (!attn_w) attn_w = (const float*)d_in[1];
  if (!attn_b) attn_b = (const float*)d_in[2];
  if (!proj_w) proj_w = (const float*)d_in[3];
  if (!proj_b) proj_b = (const float*)d_in[4];
  float* out = (float*)d_out;  // [4,2048,1024] fp32

  char* ws = (char*)d_ws;
  const size_t AWS_B = (size_t)B_ * S_ * D_ * 2;      // 16 MiB
  const size_t QKV_E = (size_t)B_ * H_ * S_ * HD_;    // 8M elems

  bf16_t* aws = (bf16_t*)ws;           // [B*S][D]
  bf16_t* wT1 = (bf16_t*)ws;           // [3072][1024] overlay (dead pre-attn)
  bf16_t* qws = (bf16_t*)(ws + AWS_B); // [B,H,S,HD]
  bf16_t* kws = qws + QKV_E;           // [B,H,S,HD]
  bf16_t* vws = kws + QKV_E;           // [B,H,HD,S]  (transposed, R10)
  bf16_t* wT2 = qws;                   // [1024][1024] overlay (post-attn)
  bf16_t* hb = (bf16_t*)d_out;         // hidden bf16 overlay in d_out
                                       // (dead until proj GEMM, R13)

  // 0. fused prep: hidden cvt (blocks 0..4095) + attn_w transpose (..7167)
  prep<<<dim3(7168), 256, 0, stream>>>(hidden, hb, attn_w, wT1);
  // 1. QKV GEMM: hidden(bf16, async-A staging) x wT1 -> q/k + V^T scatter
  gemm_bt<<<dim3(24, 64), 256, 0, stream>>>(
      hb, wT1, attn_b, nullptr, qws, kws, vws, 8192, 3072, 1024, 1, 0, 0);
  // 2. attention -> aws (overwrites wT1: dead). 256 persistent-pair blocks.
  attn_kernel<<<dim3(256), 512, 0, stream>>>(qws, kws, vws, aws);
  // 3. proj_w [1024][1024] -> wT2 bf16 (overlays qws: dead after attn)
  transpose_cvt<<<dim3(32, 32), dim3(32, 8), 0, stream>>>(proj_w, wT2, 1024, 1024);
  // 4. proj GEMM: aws(bf16) x wT2 -> out fp32 (overwrites hb scratch)
  gemm_bt<<<dim3(8, 64), 256, 0, stream>>>(
      aws, wT2, proj_b, out, nullptr, nullptr, nullptr, 8192, 1024, 1024, 0, 0, 0);
}

// Round 10
// 256.799 us; speedup vs baseline: 1.1183x; 1.1183x over previous
//
#include <hip/hip_runtime.h>
#include <hip/hip_bf16.h>
#include <stdint.h>

// B=4, S=2048, D=1024, H=16, HD=64. Inputs fp32, OUTPUT fp32.
// Intermediates bf16. Workspace 64 MiB (exact fit):
//   aws  [0, 16MiB)    bf16 [B*S][D]   (wT1 overlays; dead before attn)
//   qkv  [16, 64MiB)   bf16 q|k|v each; V stored TRANSPOSED [B,H,HD,S] (R10)
//   wT2 overlays qws, written AFTER attn consumed Q.
// R13: hidden pre-converted to bf16 into d_out (dead until proj GEMM).
// R17: attn KVBLK=128; fused prep.
// R18: GEMM K-loop -> depth-2 counted-vmcnt double-buffer (BK=64, 64KB LDS,
//      2 blocks/CU retained; vmcnt(8) in-loop, never 0; T2 slot-swizzle;
//      epilogues/tile/wave-layout identical to proven gemm_bt).
#define B_ 4
#define S_ 2048
#define D_ 1024
#define H_ 16
#define HD_ 64

typedef __bf16 bf16_t;
typedef bf16_t bf16x8 __attribute__((ext_vector_type(8)));
typedef bf16_t bf16x4 __attribute__((ext_vector_type(4)));
typedef float f32x4 __attribute__((ext_vector_type(4)));
typedef float f32x16 __attribute__((ext_vector_type(16)));

__device__ __forceinline__ bf16x8 cvt8(f32x4 lo, f32x4 hi) {
  bf16x8 r;
#pragma unroll
  for (int i = 0; i < 4; i++) {
    r[i] = (bf16_t)lo[i];
    r[i + 4] = (bf16_t)hi[i];
  }
  return r;
}

// Async global->LDS, 16B/lane; LDS dest = wave-uniform base + lane*16.
__device__ __forceinline__ void async_lds16(const bf16_t* g, bf16_t* l) {
  __builtin_amdgcn_global_load_lds(
      (const __attribute__((address_space(1))) void*)g,
      (__attribute__((address_space(3))) void*)l, 16, 0, 0);
}

// pack two f32 -> one u32 of two bf16 (elem0 = low 16 bits); compiler fuses.
__device__ __forceinline__ uint32_t pk2(float a, float b) {
  union {
    bf16_t h[2];
    uint32_t u;
  } x;
  x.h[0] = (bf16_t)a;
  x.h[1] = (bf16_t)b;
  return x.u;
}

// v_permlane32_swap_b32: a.hi_lanes <-> b.lo_lanes.
__device__ __forceinline__ void swap32(uint32_t& a, uint32_t& b) {
  asm("v_permlane32_swap_b32 %0, %1" : "+v"(a), "+v"(b));
}

union PAU {
  uint32_t w[4];
  bf16x8 v;
};

// ---------------------------------------------------------------------------
// Fused prep (R17): blocks [0,4096): hidden fp32->bf16 (8 elems/thread);
// blocks [4096,7168): attn_w [1024][3072] -> wT1 bf16 [3072][1024].
// ---------------------------------------------------------------------------
__global__ __launch_bounds__(256) void prep(
    const float* __restrict__ hidden, bf16_t* __restrict__ hb,
    const float* __restrict__ attn_w, bf16_t* __restrict__ wT1) {
  __shared__ bf16_t tile[32][33];
  const int bid = blockIdx.x;
  if (bid < 4096) {
    size_t i = ((size_t)bid * 256 + threadIdx.x) * 8;
    f32x4 lo = *(const f32x4*)(hidden + i);
    f32x4 hi = *(const f32x4*)(hidden + i + 4);
    *(bf16x8*)(hb + i) = cvt8(lo, hi);
  } else {
    const int b2 = bid - 4096;  // 0..3071
    const int c0 = (b2 % 96) * 32, r0 = (b2 / 96) * 32;
    const int tx = threadIdx.x & 31, ty = threadIdx.x >> 5;
    const int R = 1024, C = 3072;
    for (int i = ty; i < 32; i += 8)
      tile[i][tx] = (bf16_t)attn_w[(size_t)(r0 + i) * C + c0 + tx];
    __syncthreads();
    for (int i = ty; i < 32; i += 8)
      wT1[(size_t)(c0 + i) * R + r0 + tx] = tile[tx][i];
  }
}

// ---------------------------------------------------------------------------
// Weight cvt+transpose: in fp32 [R][C] -> out bf16 [C][R]. (proj_w, post-attn)
// ---------------------------------------------------------------------------
__global__ void transpose_cvt(const float* __restrict__ in,
                              bf16_t* __restrict__ out, int R, int C) {
  __shared__ bf16_t tile[32][33];
  int c0 = blockIdx.x * 32, r0 = blockIdx.y * 32;
  int tx = threadIdx.x, ty = threadIdx.y;  // 32 x 8
  for (int i = ty; i < 32; i += 8)
    tile[i][tx] = (bf16_t)in[(size_t)(r0 + i) * C + c0 + tx];
  __syncthreads();
  for (int i = ty; i < 32; i += 8)
    out[(size_t)(c0 + i) * R + r0 + tx] = tile[tx][i];
}

// ---------------------------------------------------------------------------
// GEMM R18: C[m,n] = sum_k A[m,k]*BT[n,k] + bias[n]. A,BT bf16 [rows][K].
// 128x128 tile, 4 waves (2x2), per-wave 64x64 (acc[4][4]) -- SAME output
// map and epilogues as proven gemm_bt. K-loop: BK=64, double-buffered LDS
// (2x32KB), depth-2 prefetch with counted vmcnt:
//   iter j: read tile-j frags -> lgkmcnt(0)+barrier -> restage buf with
//   tile j+2 -> 32 MFMA -> vmcnt(8) [tile j+1 landed; j+2 stays in
//   flight] + barrier. In-loop vmcnt NEVER drains to 0 (T4).
// T2 slot-swizzle both-sides: source k-off (lane&7)^(lane>>3), read col
// (ks*4+quad)^(tn&7) -> 2-way LDS reads. T5 setprio on MFMA cluster.
// T1 XCD-chunked block swizzle. mode 0: fp32 C. mode 1: QKV scatter (V^T).
// ---------------------------------------------------------------------------
__global__ __launch_bounds__(256, 2) void gemm_db(
    const bf16_t* __restrict__ Ab, const bf16_t* __restrict__ BT,
    const float* __restrict__ bias, float* __restrict__ Cout,
    bf16_t* __restrict__ qws, bf16_t* __restrict__ kws,
    bf16_t* __restrict__ vws, int M, int Nw, int K, int mode) {
  __shared__ bf16_t As[2][128 * 64];  // [buf][m][k] 32KB each
  __shared__ bf16_t Bs[2][128 * 64];  // [buf][n][k]
  const int tid = threadIdx.x;
  const int wave = tid >> 6, lane = tid & 63;
  const int quad = lane >> 4, tn = lane & 15;
  // T1 XCD-chunked swizzle (grids are multiples of 8 blocks).
  const int lid = blockIdx.y * gridDim.x + blockIdx.x;
  const int cpx = (gridDim.x * gridDim.y) >> 3;
  const int nl = (lid & 7) * cpx + (lid >> 3);
  const int m_blk = (nl / gridDim.x) * 128, n_blk = (nl % gridDim.x) * 128;
  const int wm = (wave >> 1) * 64, wn = (wave & 1) * 64;

  f32x4 acc[4][4] = {};

  // staging map: wave stages rows [wave*32,+32) of each 128x64 tile.
  // call c covers rows +c*8; lane l -> row +(l>>3), 16B slot (l&7), with
  // source col pre-swizzled by (l>>3) so linear LDS dest ends up swizzled.
  const int srowA = wave * 32 + (lane >> 3);
  const int scolS = ((lane & 7) ^ (lane >> 3)) * 8;  // swizzled k-offset
  const bf16_t* aSrc = Ab + (size_t)(m_blk + srowA) * K + scolS;
  const bf16_t* bSrc = BT + (size_t)(n_blk + srowA) * K + scolS;

#define GST(buf, jt)                                                       \
  do {                                                                     \
    _Pragma("unroll") for (int c = 0; c < 4; c++) {                        \
      async_lds16(aSrc + (size_t)(jt)*64 + (size_t)c * 8 * K,              \
                  &As[buf][(wave * 32 + c * 8) * 64]);                     \
      async_lds16(bSrc + (size_t)(jt)*64 + (size_t)c * 8 * K,              \
                  &Bs[buf][(wave * 32 + c * 8) * 64]);                     \
    }                                                                      \
  } while (0)

  const int NT = K >> 6;  // 16 for K=1024
  GST(0, 0);
  GST(1, 1);
  asm volatile("s_waitcnt vmcnt(8)" ::: "memory");  // tile0's 8 calls done
  __builtin_amdgcn_s_barrier();

  int cur = 0;
  for (int j = 0; j < NT; ++j) {
    // 1. read ALL tile-j fragments into registers (swizzled cols)
    bf16x8 af[4][2], bfv[4][2];
#pragma unroll
    for (int mi = 0; mi < 4; mi++)
#pragma unroll
      for (int ks = 0; ks < 2; ks++)
        af[mi][ks] = *(const bf16x8*)&As[cur][(wm + mi * 16 + tn) * 64 +
                                             (((ks * 4 + quad) ^ (tn & 7)) * 8)];
#pragma unroll
    for (int ni = 0; ni < 4; ni++)
#pragma unroll
      for (int ks = 0; ks < 2; ks++)
        bfv[ni][ks] = *(const bf16x8*)&Bs[cur][(wn + ni * 16 + tn) * 64 +
                                              (((ks * 4 + quad) ^ (tn & 7)) * 8)];
    asm volatile("s_waitcnt lgkmcnt(0)" ::: "memory");  // reads retired
    __builtin_amdgcn_s_barrier();  // all waves done reading buf[cur]
    // 2. restage buf[cur] with tile j+2 (overlaps the MFMA below)
    if (j + 2 < NT) GST(cur, j + 2);
    // 3. compute tile j from registers
    __builtin_amdgcn_s_setprio(1);
#pragma unroll
    for (int ks = 0; ks < 2; ks++)
#pragma unroll
      for (int mi = 0; mi < 4; mi++)
#pragma unroll
        for (int ni = 0; ni < 4; ni++)
          acc[mi][ni] = __builtin_amdgcn_mfma_f32_16x16x32_bf16(
              af[mi][ks], bfv[ni][ks], acc[mi][ni], 0, 0, 0);
    __builtin_amdgcn_s_setprio(0);
    // 4. tile j+1 (older 8 calls) landed; tile j+2 may stay in flight
    if (j + 1 < NT) {
      if (j + 2 < NT)
        asm volatile("s_waitcnt vmcnt(8)" ::: "memory");
      else
        asm volatile("s_waitcnt vmcnt(0)" ::: "memory");
      __builtin_amdgcn_s_barrier();
    }
    cur ^= 1;
  }
#undef GST

  // Epilogue (verbatim from gemm_bt). C/D: col(n)=lane&15, row(m)=quad*4+r.
  if (mode == 0) {  // fp32 final store
#pragma unroll
    for (int ni = 0; ni < 4; ni++) {
      int n = n_blk + wn + ni * 16 + tn;
      float bv = bias[n];
#pragma unroll
      for (int mi = 0; mi < 4; mi++)
#pragma unroll
        for (int r = 0; r < 4; r++) {
          int m = m_blk + wm + mi * 16 + quad * 4 + r;
          Cout[(size_t)m * Nw + n] = acc[mi][ni][r] + bv;
        }
    }
  } else {  // QKV scatter. sec is block-uniform (n_blk multiple of 128).
#pragma unroll
    for (int ni = 0; ni < 4; ni++) {
      int n = n_blk + wn + ni * 16 + tn;
      int sec = n >> 10;
      int hn = n & 1023;
      int hh = hn >> 6, hd = hn & 63;
      float bv = bias[n];
      if (sec == 2) {  // V^T [bb][H][HD][S]: 4 consecutive s -> 8B store
#pragma unroll
        for (int mi = 0; mi < 4; mi++) {
          int m = m_blk + wm + mi * 16 + quad * 4;
          int bb = m >> 11, s = m & 2047;
          bf16x4 pk;
#pragma unroll
          for (int r = 0; r < 4; r++) pk[r] = (bf16_t)(acc[mi][ni][r] + bv);
          *(bf16x4*)&vws[((size_t)(bb * H_ + hh) * HD_ + hd) * S_ + s] = pk;
        }
      } else {
        bf16_t* dst = (sec == 0) ? qws : kws;
#pragma unroll
        for (int mi = 0; mi < 4; mi++)
#pragma unroll
          for (int r = 0; r < 4; r++) {
            int m = m_blk + wm + mi * 16 + quad * 4 + r;
            int bb = m >> 11, s = m & 2047;
            dst[((size_t)(bb * H_ + hh) * S_ + s) * HD_ + hd] =
                (bf16_t)(acc[mi][ni][r] + bv);
          }
      }
    }
  }
}

// ---------------------------------------------------------------------------
// Causal flash attention, R17 (unchanged): persistent-pair blocks, KVBLK=128.
// ---------------------------------------------------------------------------
__global__ __launch_bounds__(512, 2) void attn_kernel(
    const bf16_t* __restrict__ Qw, const bf16_t* __restrict__ Kw,
    const bf16_t* __restrict__ VTw, bf16_t* __restrict__ Ow) {
  __shared__ bf16_t Ks[2][128 * 64];  // [key][hd], slot-swizzled (32KB)
  __shared__ bf16_t Vt[2][64 * 128];  // [hd][key], slot-swizzled (32KB)

  const int tid = threadIdx.x;
  const int wave = tid >> 6, lane = tid & 63;  // wave 0..7
  const int lq = lane & 31;   // query slot (and d-col) index within wave
  const int h = lane >> 5;    // half: k-subrange selector in A/B frags
  const int qoff = h * 4;     // C-layout row offset
  const int bid = blockIdx.x;          // 0..255
  const int j = bid >> 3;              // 0..31 within this XCD
  const int bh = (bid & 7) * 8 + (j >> 2);
  const int pj = j & 3;                // pair index 0..3

  const bf16_t* Qb = Qw + (size_t)bh * S_ * HD_;
  const bf16_t* Kb = Kw + (size_t)bh * S_ * HD_;
  const bf16_t* VTb = VTw + (size_t)bh * HD_ * S_;

  const float kScale = 0.125f * 1.44269504088896f;  // 1/sqrt(64) * log2(e)

  // ones B-frag for the row-sum MFMA
  bf16x8 onesf;
#pragma unroll
  for (int jj = 0; jj < 8; jj++) onesf[jj] = (bf16_t)1.0f;

  const float NEG = -30000.0f;
  const int b = bh >> 4, hh = bh & 15;

  // staging (per wave 4 async calls x 1KB):
  const int krow = wave * 16 + (lane >> 3);
  const int ksl = lane & 7;
  const bf16_t* kpA = Kb + (size_t)krow * HD_ + ((ksl ^ (krow & 7)) * 8);
  const bf16_t* kpB =
      Kb + (size_t)(krow + 8) * HD_ + ((ksl ^ ((krow + 8) & 7)) * 8);
  const int vrow = wave * 8 + (lane >> 4);
  const int vsl = lane & 15;
  const bf16_t* vpA = VTb + (size_t)vrow * S_ + ((vsl ^ (vrow & 7)) * 8);
  const bf16_t* vpB =
      VTb + (size_t)(vrow + 4) * S_ + ((vsl ^ ((vrow + 4) & 7)) * 8);

#define STAGE(buf, kt)                                                     \
  do {                                                                     \
    async_lds16(kpA + (size_t)(kt) * (128 * HD_), &Ks[buf][wave * 1024]);  \
    async_lds16(kpB + (size_t)(kt) * (128 * HD_),                          \
                &Ks[buf][wave * 1024 + 512]);                              \
    async_lds16(vpA + (size_t)(kt) * 128, &Vt[buf][wave * 1024]);          \
    async_lds16(vpB + (size_t)(kt) * 128, &Vt[buf][wave * 1024 + 512]);    \
  } while (0)

  for (int task = 0; task < 2; task++) {
    const int qt = task == 0 ? (7 - pj) : pj;  // long first, then short
    const int qb = qt * 256;
    const int qa = qb + ((lq >> 3) << 6) + wave * 8 + (lq & 7);

    // Q B-frags: B[k][n=lq], k = h*8+j within each 16-wide slice kg.
    bf16x8 qf[4];
#pragma unroll
    for (int kg = 0; kg < 4; kg++) {
      bf16x8 v = *(const bf16x8*)&Qb[(size_t)qa * HD_ + kg * 16 + h * 8];
#pragma unroll
      for (int jj = 0; jj < 8; jj++) v[jj] = (bf16_t)((float)v[jj] * kScale);
      qf[kg] = v;
    }

    f32x16 o0 = {}, o1 = {};  // O[q-slot][d]: d = dblk*32+lq
    f32x16 ls = {};           // row-sum accumulator (same C-layout as o)
    float mrow = NEG;

    const int kt_max = (qb + 255) >> 7;  // inclusive; 2qt+1

    if (task) __syncthreads();  // all waves done reading prev task's bufs
    STAGE(0, 0);

    for (int kt = 0; kt <= kt_max; kt++) {
      __syncthreads();  // drains vmcnt: buf[kt&1] staged; prev readers done
      if (kt < kt_max) STAGE((kt + 1) & 1, kt + 1);

      const bf16_t* KsB = Ks[kt & 1];
      const bf16_t* VtB = Vt[kt & 1];
      const int rsl = lq & 7;  // row-swizzle (same for lq, 32+lq, b*32+lq)

      // QK^T swapped: st[bk] = keys [bk*32, +32) of this 128-key tile.
      f32x16 st[4] = {{}, {}, {}, {}};
      __builtin_amdgcn_s_setprio(1);
#pragma unroll
      for (int kg = 0; kg < 4; kg++) {
        const int slot = kg * 2 + h;
#pragma unroll
        for (int bk = 0; bk < 4; bk++) {
          bf16x8 kf = *(const bf16x8*)&KsB[(bk * 32 + lq) * 64 +
                                           ((slot ^ rsl) * 8)];
          st[bk] =
              __builtin_amdgcn_mfma_f32_32x32x16_bf16(kf, qf[kg], st[bk], 0, 0, 0);
        }
      }
      __builtin_amdgcn_s_setprio(0);
      // causal mask only on the last two tiles of a task.
      if (kt * 128 + 127 > qb) {
#pragma unroll
        for (int bk = 0; bk < 4; bk++)
#pragma unroll
          for (int r = 0; r < 16; r++) {
            int key = kt * 128 + bk * 32 + (r & 3) + 8 * (r >> 2) + qoff;
            if (key > qa) st[bk][r] = NEG;
          }
      }
      // row max: in-lane tree (63 fmax) + one cross-half exchange
      float mx;
      {
        float m4[4];
#pragma unroll
        for (int bk = 0; bk < 4; bk++) {
          float a0 = fmaxf(fmaxf(st[bk][0], st[bk][1]),
                           fmaxf(st[bk][2], st[bk][3]));
          float a1 = fmaxf(fmaxf(st[bk][4], st[bk][5]),
                           fmaxf(st[bk][6], st[bk][7]));
          float a2 = fmaxf(fmaxf(st[bk][8], st[bk][9]),
                           fmaxf(st[bk][10], st[bk][11]));
          float a3 = fmaxf(fmaxf(st[bk][12], st[bk][13]),
                           fmaxf(st[bk][14], st[bk][15]));
          m4[bk] = fmaxf(fmaxf(a0, a1), fmaxf(a2, a3));
        }
        mx = fmaxf(fmaxf(m4[0], m4[1]), fmaxf(m4[2], m4[3]));
        mx = fmaxf(mx, __shfl_xor(mx, 32, 64));
      }

      // T13 defer-max: rescale only when max grew by > 8 (log2 domain)
      if (__any(mx > mrow + 8.f)) {
        float mnew = fmaxf(mrow, mx);
        float alpha = exp2f(mrow - mnew);
        mrow = mnew;
#pragma unroll
        for (int r = 0; r < 16; r++) {
          float ar = __shfl(alpha, (r & 3) + 8 * (r >> 2) + qoff, 64);
          o0[r] *= ar;
          o1[r] *= ar;
          ls[r] *= ar;
        }
      }
      // P = exp2(st - m) (bounded by 2^8 when deferred)
#pragma unroll
      for (int bk = 0; bk < 4; bk++)
#pragma unroll
        for (int r = 0; r < 16; r++) st[bk][r] = exp2f(st[bk][r] - mrow);

      // P -> PV A-frags, in-register: per 32-key block, pack + permlane.
      PAU pa[8];
#pragma unroll
      for (int bk = 0; bk < 4; bk++) {
        uint32_t w[8];
#pragma unroll
        for (int i = 0; i < 8; i++)
          w[i] = pk2(st[bk][2 * i], st[bk][2 * i + 1]);
        swap32(w[0], w[2]);
        swap32(w[1], w[3]);
        swap32(w[4], w[6]);
        swap32(w[5], w[7]);
        pa[2 * bk].w[0] = w[0];
        pa[2 * bk].w[1] = w[1];
        pa[2 * bk].w[2] = w[2];
        pa[2 * bk].w[3] = w[3];
        pa[2 * bk + 1].w[0] = w[4];
        pa[2 * bk + 1].w[1] = w[5];
        pa[2 * bk + 1].w[2] = w[6];
        pa[2 * bk + 1].w[3] = w[7];
      }

      // PV: O[q][d] += P*V; B-frag = Vt[d = dblk*32+lq][key kg*16+8h+j].
      __builtin_amdgcn_s_setprio(1);
#pragma unroll
      for (int kg = 0; kg < 8; kg++) {
        const int slot = kg * 2 + h;  // 0..15
        bf16x8 vf0 = *(const bf16x8*)&VtB[lq * 128 + ((slot ^ rsl) * 8)];
        bf16x8 vf1 =
            *(const bf16x8*)&VtB[(32 + lq) * 128 + ((slot ^ rsl) * 8)];
        o0 = __builtin_amdgcn_mfma_f32_32x32x16_bf16(pa[kg].v, vf0, o0, 0, 0, 0);
        o1 = __builtin_amdgcn_mfma_f32_32x32x16_bf16(pa[kg].v, vf1, o1, 0, 0, 0);
        ls = __builtin_amdgcn_mfma_f32_32x32x16_bf16(pa[kg].v, onesf, ls, 0, 0, 0);
      }
      __builtin_amdgcn_s_setprio(0);
    }

    // normalize + store merged heads [b][s][hh*64+d] (bf16). ls reg-local.
#pragma unroll
    for (int r = 0; r < 16; r++) {
      int qr = (r & 3) + 8 * (r >> 2) + qoff;  // q-slot of this C row
      int q = qb + ((qr >> 3) << 6) + wave * 8 + (qr & 7);  // striped remap
      float inv = 1.f / fmaxf(ls[r], 1e-30f);
      bf16_t* dst = Ow + (size_t)(b * S_ + q) * D_ + hh * HD_;
      dst[lq] = (bf16_t)(o0[r] * inv);
      dst[32 + lq] = (bf16_t)(o1[r] * inv);
    }
  }
#undef STAGE
}

// ---------------------------------------------------------------------------
extern "C" void kernel_launch(void* const* d_in, const int* in_sizes, int n_in,
                              void* d_out, int out_size, void* d_ws,
                              size_t ws_size, hipStream_t stream) {
  const float* hidden = nullptr;
  const float* attn_w = nullptr;
  const float* attn_b = nullptr;
  const float* proj_w = nullptr;
  const float* proj_b = nullptr;
  for (int i = 0; i < n_in; ++i) {
    switch (in_sizes[i]) {
      case 8388608: hidden = (const float*)d_in[i]; break;
      case 3145728: attn_w = (const float*)d_in[i]; break;
      case 3072:    attn_b = (const float*)d_in[i]; break;
      case 1048576: proj_w = (const float*)d_in[i]; break;
      case 1024:    proj_b = (const float*)d_in[i]; break;
      default: break;
    }
  }
  if (!hidden) hidden = (const float*)d_in[0];
  if (!attn_w) attn_w = (const float*)d_in[1];
  if (!attn_b) attn_b = (const float*)d_in[2];
  if (!proj_w) proj_w = (const float*)d_in[3];
  if (!proj_b) proj_b = (const float*)d_in[4];
  float* out = (float*)d_out;  // [4,2048,1024] fp32

  char* ws = (char*)d_ws;
  const size_t AWS_B = (size_t)B_ * S_ * D_ * 2;      // 16 MiB
  const size_t QKV_E = (size_t)B_ * H_ * S_ * HD_;    // 8M elems

  bf16_t* aws = (bf16_t*)ws;           // [B*S][D]
  bf16_t* wT1 = (bf16_t*)ws;           // [3072][1024] overlay (dead pre-attn)
  bf16_t* qws = (bf16_t*)(ws + AWS_B); // [B,H,S,HD]
  bf16_t* kws = qws + QKV_E;           // [B,H,S,HD]
  bf16_t* vws = kws + QKV_E;           // [B,H,HD,S]  (transposed, R10)
  bf16_t* wT2 = qws;                   // [1024][1024] overlay (post-attn)
  bf16_t* hb = (bf16_t*)d_out;         // hidden bf16 overlay in d_out
                                       // (dead until proj GEMM, R13)

  // 0. fused prep: hidden cvt (blocks 0..4095) + attn_w transpose (..7167)
  prep<<<dim3(7168), 256, 0, stream>>>(hidden, hb, attn_w, wT1);
  // 1. QKV GEMM (R18 depth-2 dbuf): hidden(bf16) x wT1 -> q/k + V^T scatter
  gemm_db<<<dim3(24, 64), 256, 0, stream>>>(
      hb, wT1, attn_b, nullptr, qws, kws, vws, 8192, 3072, 1024, 1);
  // 2. attention -> aws (overwrites wT1: dead). 256 persistent-pair blocks.
  attn_kernel<<<dim3(256), 512, 0, stream>>>(qws, kws, vws, aws);
  // 3. proj_w [1024][1024] -> wT2 bf16 (overlays qws: dead after attn)
  transpose_cvt<<<dim3(32, 32), dim3(32, 8), 0, stream>>>(proj_w, wT2, 1024, 1024);
  // 4. proj GEMM (R18): aws(bf16) x wT2 -> out fp32 (overwrites hb scratch)
  gemm_db<<<dim3(8, 64), 256, 0, stream>>>(
      aws, wT2, proj_b, out, nullptr, nullptr, nullptr, 8192, 1024, 1024, 0);
}